// Round 13
// baseline (1016.975 us; speedup 1.0000x reference)
//
#include <hip/hip_runtime.h>

#define NCH 32

typedef __attribute__((ext_vector_type(8))) __bf16 bf16x8;
typedef __attribute__((ext_vector_type(4))) float  f32x4;

union bcast16 { int4 i; bf16x8 h; };

static __device__ __forceinline__ void split8(const float* x, bf16x8& hi, bf16x8& lo)
{
#pragma unroll
    for (int e = 0; e < 8; ++e) {
        __bf16 h = (__bf16)x[e];
        hi[e] = h;
        lo[e] = (__bf16)(x[e] - (float)h);
    }
}

static __device__ __forceinline__ void split8m(
    const f32x4& x0, const f32x4& x1, float m, bf16x8& hi, bf16x8& lo)
{
    float x[8] = {x0.x * m, x0.y * m, x0.z * m, x0.w * m,
                  x1.x * m, x1.y * m, x1.z * m, x1.w * m};
#pragma unroll
    for (int e = 0; e < 8; ++e) {
        __bf16 h = (__bf16)x[e];
        hi[e] = h;
        lo[e] = (__bf16)(x[e] - (float)h);
    }
}

static __device__ __forceinline__ void mfma3(
    const bf16x8& ah, const bf16x8& al,
    const bf16x8& wh, const bf16x8& wl, f32x4& acc)
{
    acc = __builtin_amdgcn_mfma_f32_16x16x32_bf16(ah, wh, acc, 0, 0, 0);
    acc = __builtin_amdgcn_mfma_f32_16x16x32_bf16(al, wh, acc, 0, 0, 0);
    acc = __builtin_amdgcn_mfma_f32_16x16x32_bf16(ah, wl, acc, 0, 0, 0);
}

static __device__ __forceinline__ ushort f2bf(float x)
{
    __bf16 b = (__bf16)x;
    return *(const ushort*)&b;
}

// Device-scope grid barrier (persistent-kernel substitute for grid.sync()).
// Monotonic arrival counter in global memory: phase k waits for count >= k*nblk.
// release: __threadfence (all threads) + __syncthreads, then thread0 arrives;
// acquire: spin via device atomic, __syncthreads, __threadfence (inv caches).
static __device__ __forceinline__ void gsync(
    unsigned* __restrict__ bar, unsigned phase, unsigned nblk)
{
    __threadfence();
    __syncthreads();
    if (threadIdx.x == 0) {
        atomicAdd(bar, 1u);
        const unsigned target = phase * nblk;
        while (atomicAdd(bar, 0u) < target) __builtin_amdgcn_s_sleep(4);
    }
    __syncthreads();
    __threadfence();
}

// One factorized 1-D sparse conv pass — round-12 champion body verbatim
// (branch-free taps, LDS-staged coalesced C store, fused optional stats).
template<int IN_BF16, int DO_STATS>
static __device__ void conv_pass(
    const void* __restrict__ fin, const float* __restrict__ W,
    const int* __restrict__ idx, ushort* __restrict__ ob, int n,
    float* __restrict__ stats,
    float (*red)[4][16], ushort (*ctile)[16][NCH])
{
    const int lane = threadIdx.x & 63;
    const int wv   = threadIdx.x >> 6;
    const int r16  = lane & 15;
    const int g    = lane >> 4;
    const int c0   = g * 8;

    const float*  ff = (const float*)fin;
    const ushort* fb = (const ushort*)fin;

    // B fragments: 3 taps x 2 output halves, hi/lo split (fp32-exact weights).
    bf16x8 bh[3][2], bl[3][2];
#pragma unroll
    for (int k = 0; k < 3; ++k) {
#pragma unroll
        for (int h = 0; h < 2; ++h) {
            float w8[8];
#pragma unroll
            for (int e = 0; e < 8; ++e)
                w8[e] = W[k * NCH * NCH + (c0 + e) * NCH + (h * 16 + r16)];
            split8(w8, bh[k][h], bl[k][h]);
        }
    }

    const int ntiles = (n + 15) >> 4;
    const int nw = gridDim.x * 4;
    float s0 = 0.f, q0 = 0.f, s1 = 0.f, q1 = 0.f;

    for (int tile = blockIdx.x * 4 + wv; tile < ntiles; tile += nw) {
        const int  tb  = tile << 4;
        const int  p   = tb + r16;
        const bool pin = (p < n);
        const int  pc  = pin ? p : 0;

        int i0 = idx[pc];
        int i2 = idx[2 * (size_t)n + pc];
        const bool v0 = pin && (i0 < n);
        const bool v2 = pin && (i2 < n);

        f32x4 a0 = {0.f, 0.f, 0.f, 0.f};
        f32x4 a1 = {0.f, 0.f, 0.f, 0.f};

        if constexpr (IN_BF16) {
            int4 rawc = *(const int4*)(fb + (size_t)pc * NCH + c0);
            int4 raw0 = *(const int4*)(fb + (size_t)(v0 ? i0 : 0) * NCH + c0);
            int4 raw2 = *(const int4*)(fb + (size_t)(v2 ? i2 : 0) * NCH + c0);

            if (!pin) { rawc.x = 0; rawc.y = 0; rawc.z = 0; rawc.w = 0; }
            bcast16 uc; uc.i = rawc;
            a0 = __builtin_amdgcn_mfma_f32_16x16x32_bf16(uc.h, bh[1][0], a0, 0, 0, 0);
            a0 = __builtin_amdgcn_mfma_f32_16x16x32_bf16(uc.h, bl[1][0], a0, 0, 0, 0);
            a1 = __builtin_amdgcn_mfma_f32_16x16x32_bf16(uc.h, bh[1][1], a1, 0, 0, 0);
            a1 = __builtin_amdgcn_mfma_f32_16x16x32_bf16(uc.h, bl[1][1], a1, 0, 0, 0);

            if (!v0) { raw0.x = 0; raw0.y = 0; raw0.z = 0; raw0.w = 0; }
            bcast16 u0; u0.i = raw0;
            a0 = __builtin_amdgcn_mfma_f32_16x16x32_bf16(u0.h, bh[0][0], a0, 0, 0, 0);
            a0 = __builtin_amdgcn_mfma_f32_16x16x32_bf16(u0.h, bl[0][0], a0, 0, 0, 0);
            a1 = __builtin_amdgcn_mfma_f32_16x16x32_bf16(u0.h, bh[0][1], a1, 0, 0, 0);
            a1 = __builtin_amdgcn_mfma_f32_16x16x32_bf16(u0.h, bl[0][1], a1, 0, 0, 0);

            if (!v2) { raw2.x = 0; raw2.y = 0; raw2.z = 0; raw2.w = 0; }
            bcast16 u2; u2.i = raw2;
            a0 = __builtin_amdgcn_mfma_f32_16x16x32_bf16(u2.h, bh[2][0], a0, 0, 0, 0);
            a0 = __builtin_amdgcn_mfma_f32_16x16x32_bf16(u2.h, bl[2][0], a0, 0, 0, 0);
            a1 = __builtin_amdgcn_mfma_f32_16x16x32_bf16(u2.h, bh[2][1], a1, 0, 0, 0);
            a1 = __builtin_amdgcn_mfma_f32_16x16x32_bf16(u2.h, bl[2][1], a1, 0, 0, 0);
        } else {
            const f32x4* rpc = (const f32x4*)(ff + (size_t)pc * NCH + c0);
            f32x4 xc0 = __builtin_nontemporal_load(rpc);
            f32x4 xc1 = __builtin_nontemporal_load(rpc + 1);
            const f32x4* rp0 = (const f32x4*)(ff + (size_t)(v0 ? i0 : 0) * NCH + c0);
            f32x4 x00 = __builtin_nontemporal_load(rp0);
            f32x4 x01 = __builtin_nontemporal_load(rp0 + 1);
            const f32x4* rp2 = (const f32x4*)(ff + (size_t)(v2 ? i2 : 0) * NCH + c0);
            f32x4 x20 = __builtin_nontemporal_load(rp2);
            f32x4 x21 = __builtin_nontemporal_load(rp2 + 1);

            bf16x8 ah, al;
            split8m(xc0, xc1, pin ? 1.f : 0.f, ah, al);
            mfma3(ah, al, bh[1][0], bl[1][0], a0);
            mfma3(ah, al, bh[1][1], bl[1][1], a1);
            split8m(x00, x01, v0 ? 1.f : 0.f, ah, al);
            mfma3(ah, al, bh[0][0], bl[0][0], a0);
            mfma3(ah, al, bh[0][1], bl[0][1], a1);
            split8m(x20, x21, v2 ? 1.f : 0.f, ah, al);
            mfma3(ah, al, bh[2][0], bl[2][0], a0);
            mfma3(ah, al, bh[2][1], bl[2][1], a1);
        }

        // ---- store C (bf16): full tiles via per-wave LDS, 16B/lane ----
        if (tb + 16 <= n) {
#pragma unroll
            for (int r = 0; r < 4; ++r) {
                ctile[wv][g * 4 + r][r16]      = f2bf(a0[r]);
                ctile[wv][g * 4 + r][r16 + 16] = f2bf(a1[r]);
            }
            uint4 rowv = *(const uint4*)((const char*)&ctile[wv][0][0] + lane * 16);
            *(uint4*)(ob + (size_t)tb * NCH + lane * 8) = rowv;
        } else {
#pragma unroll
            for (int r = 0; r < 4; ++r) {
                int prow = tb + g * 4 + r;
                if (prow < n) {
                    ushort* o = ob + (size_t)prow * NCH + r16;
                    o[0]  = f2bf(a0[r]);
                    o[16] = f2bf(a1[r]);
                }
            }
        }

        if constexpr (DO_STATS) {
#pragma unroll
            for (int r = 0; r < 4; ++r) {
                s0 += a0[r]; q0 = fmaf(a0[r], a0[r], q0);
                s1 += a1[r]; q1 = fmaf(a1[r], a1[r], q1);
            }
        }
    }

    if constexpr (DO_STATS) {
        s0 += __shfl_xor(s0, 16); s0 += __shfl_xor(s0, 32);
        q0 += __shfl_xor(q0, 16); q0 += __shfl_xor(q0, 32);
        s1 += __shfl_xor(s1, 16); s1 += __shfl_xor(s1, 32);
        q1 += __shfl_xor(q1, 16); q1 += __shfl_xor(q1, 32);
        if (lane < 16) {
            red[wv][0][r16] = s0;
            red[wv][1][r16] = q0;
            red[wv][2][r16] = s1;
            red[wv][3][r16] = q1;
        }
        __syncthreads();
        if (threadIdx.x < 64) {
            int vsel = threadIdx.x >> 4;
            int ch   = threadIdx.x & 15;
            float t = red[0][vsel][ch] + red[1][vsel][ch] +
                      red[2][vsel][ch] + red[3][vsel][ch];
            int channel = (vsel & 2) ? (ch + 16) : ch;
            atomicAdd(stats + ((vsel & 1) ? NCH : 0) + channel, t);
        }
        __syncthreads();   // red[] reused only after the next grid barrier
    }
}

// BN + ReLU: bf16 h3 -> fp32 out, grid-stride (stride multiple of 8 float4s
// -> channel quad fixed per thread, scale/shift computed once).
static __device__ void bn_pass(
    const ushort* __restrict__ h3, float* __restrict__ out,
    const float* __restrict__ stats,
    const float* __restrict__ gamma, const float* __restrict__ beta, int n)
{
    long total4 = (long)n * NCH / 4;
    long stride = (long)gridDim.x * 256;
    long tid = (long)blockIdx.x * 256 + threadIdx.x;

    int ch0 = ((int)(tid & 7)) * 4;
    float inv_n = 1.f / (float)n;
    float scale[4], shift[4];
#pragma unroll
    for (int j = 0; j < 4; ++j) {
        int ch = ch0 + j;
        float mean = stats[ch] * inv_n;
        float var = stats[NCH + ch] * inv_n - mean * mean;
        scale[j] = gamma[ch] * rsqrtf(var + 1e-5f);
        shift[j] = beta[ch] - mean * scale[j];
    }

    for (long i = tid; i < total4; i += stride) {
        ushort4 v = ((const ushort4*)h3)[i];
        ushort u[4] = {v.x, v.y, v.z, v.w};
        float r[4];
#pragma unroll
        for (int j = 0; j < 4; ++j) {
            float x = __uint_as_float(((unsigned)u[j]) << 16);
            float o = fmaf(x, scale[j], shift[j]);
            r[j] = o > 0.f ? o : 0.f;
        }
        f32x4 o4 = {r[0], r[1], r[2], r[3]};
        __builtin_nontemporal_store(o4, (f32x4*)out + i);
    }
}

// Persistent mega-kernel: conv1 | conv2 | conv3+stats | BN+ReLU, separated by
// software grid barriers. 1024 blocks @ launch_bounds(256,4): 4 blocks/CU vs
// >=8-block capacity at 48 VGPR -> co-residency with 2x margin (spin-safe).
// Round-7 data: 1024 vs 2048 blocks is conv-neutral (79.4 vs 79.8 us).
__global__ __launch_bounds__(256, 4) void fused_all_kernel(
    const float* __restrict__ feats, const float* __restrict__ W1,
    const float* __restrict__ W2, const float* __restrict__ W3,
    const float* __restrict__ gamma, const float* __restrict__ beta,
    const int* __restrict__ nbr, float* __restrict__ out,
    ushort* __restrict__ h1, ushort* __restrict__ h2,
    float* __restrict__ stats, unsigned* __restrict__ bar, int n)
{
    __shared__ float  red[4][4][16];
    __shared__ ushort ctile[4][16][NCH];

    const unsigned nblk = gridDim.x;

    // zero BN accumulators (consumed in phase 3, two barriers later)
    if (blockIdx.x == 0 && threadIdx.x < 2 * NCH) stats[threadIdx.x] = 0.f;

    // phase 1: conv axis 2 (z), fp32 feats -> bf16 h1
    conv_pass<0, 0>(feats, W1, nbr + (size_t)2 * 3 * n, h1, n, nullptr, red, ctile);
    gsync(bar, 1, nblk);
    // phase 2: conv axis 1 (y), bf16 h1 -> bf16 h2
    conv_pass<1, 0>(h1, W2, nbr + (size_t)1 * 3 * n, h2, n, nullptr, red, ctile);
    gsync(bar, 2, nblk);
    // phase 3: conv axis 0 (x), bf16 h2 -> bf16 h3 (reuses h1), fused stats
    conv_pass<1, 1>(h2, W3, nbr + (size_t)0 * 3 * n, h1, n, stats, red, ctile);
    gsync(bar, 3, nblk);
    // phase 4: BN + ReLU, bf16 h3 -> fp32 out
    bn_pass(h1, out, stats, gamma, beta, n);
}

extern "C" void kernel_launch(void* const* d_in, const int* in_sizes, int n_in,
                              void* d_out, int out_size, void* d_ws, size_t ws_size,
                              hipStream_t stream)
{
    const float* feats = (const float*)d_in[0];
    const float* W1    = (const float*)d_in[1];
    const float* W2    = (const float*)d_in[2];
    const float* W3    = (const float*)d_in[3];
    const float* gamma = (const float*)d_in[4];
    const float* beta  = (const float*)d_in[5];
    const int*   nbr   = (const int*)d_in[6];   // [3 axes][3 taps][n]

    int n = in_sizes[0] / NCH;

    float*    hout  = (float*)d_out;                    // final out (fp32)
    ushort*   h1    = (ushort*)d_ws;                    // n*32 bf16; h3 reuses
    ushort*   h2    = h1 + (size_t)n * NCH;             // n*32 bf16
    float*    stats = (float*)(h2 + (size_t)n * NCH);   // 64 floats
    unsigned* bar   = (unsigned*)(stats + 2 * NCH);     // barrier counter

    // ws is poisoned each call: the barrier counter must start at 0
    hipMemsetAsync(bar, 0, sizeof(unsigned), stream);

    fused_all_kernel<<<1024, 256, 0, stream>>>(
        feats, W1, W2, W3, gamma, beta, nbr, hout, h1, h2, stats, bar, n);
}